// Round 10
// baseline (329.304 us; speedup 1.0000x reference)
//
#include <hip/hip_runtime.h>
#include <hip/hip_bf16.h>

// GCN 2-layer: out = A' relu(A' (xW1) + b1) W2 + b2, A' = D^-1/2 (A+I) D^-1/2
// R19: post-mortem R18: WX=1 X-dedup neutral (dup X reads were L2 hits ->
// traffic model = L2-miss bytes). gather_gemm diagnosed latency-bound:
// 11 B/cy/CU, all pipes idle, occupancy grid-capped at 12 waves/CU with
// VGPR=52 (headroom unused).
//  - gemm1 reverted to R16's proven <512,128,32,4,2,512>.
//  - k_gather_gemm phase 1: 2-node-per-thread interleaved gather (dual edge
//    cursors + dual accumulators) -> 2x outstanding loads per wave, using the
//    idle VGPRs. Grid/waves unchanged.
// R16 base: fused gather1+layer2-GEMM; fragment-major prepped weights;
// ushort elist; bf16 Hs/Hs2; 5 kernels + 1 memset.

typedef __attribute__((ext_vector_type(8))) short short8;
typedef __attribute__((ext_vector_type(4))) float f32x4;

#define BSHIFT 9
#define BSIZE 512
constexpr int NBMAX = 128;
constexpr int CAP = 32768;   // pair slots per coarse bucket (mean ~16.3K)
constexpr int CHUNK = 4096;  // edges per binA block

__device__ __forceinline__ unsigned short bf16_bits(float f) {
  __hip_bfloat16 h = __float2bfloat16(f);
  return *(unsigned short*)&h;
}
__device__ __forceinline__ float bf16_f(unsigned short u) {
  __hip_bfloat16 h = *(__hip_bfloat16*)&u;
  return __bfloat162float(h);
}
__device__ __forceinline__ void gload_lds16(const void* g, void* l) {
  __builtin_amdgcn_global_load_lds(
      (const __attribute__((address_space(1))) unsigned*)g,
      (__attribute__((address_space(3))) unsigned*)l, 16, 0, 0);
}
__device__ __forceinline__ int edge_at(const void* p, long long i, int is64) {
  return is64 ? (int)((const long long*)p)[i] : ((const int*)p)[i];
}

// Coarse binning (blocks < nchunks): LDS counting-sort of a 4096-edge chunk by
// bucket = d>>9, flush contiguous runs into per-bucket pair regions.
// Blocks >= nchunks: weight prep, fp32 W[K,N] -> FRAGMENT-MAJOR bf16 hi/lo:
//   out[o], o = ((t*(N/16) + jt)*4 + fq)*128 + fm*8 + e
//   holds W[k = t*32 + fq*8 + e][n = jt*16 + fm]
// so each K-step's B image is a contiguous N*32-ushort slice in MFMA fragment
// order (lane = fq*16+fm reads its own 16B at lane*16).
__global__ __launch_bounds__(256) void k_binA(
    const void* __restrict__ eidx, int* __restrict__ ccur,
    unsigned* __restrict__ pairs,
    const float* __restrict__ W1, unsigned short* __restrict__ W1h,
    unsigned short* __restrict__ W1l,
    const float* __restrict__ W2, unsigned short* __restrict__ W2h,
    unsigned short* __restrict__ W2l, int E, int NB, int nchunks) {
  const int tid = threadIdx.x;
  if ((int)blockIdx.x >= nchunks) {  // ---- weight prep ----
    int o = ((int)blockIdx.x - nchunks) * 256 + tid;
    const float* W; unsigned short *Wh, *Wl; int Nn;
    if (o < 512 * 128) { W = W1; Wh = W1h; Wl = W1l; Nn = 128; }
    else { o -= 512 * 128; if (o >= 128 * 64) return;
           W = W2; Wh = W2h; Wl = W2l; Nn = 64; }
    int e = o & 7;
    int fm = (o >> 3) & 15;
    int fq = (o >> 7) & 3;
    int rest = o >> 9;            // t*(Nn/16) + jt
    int nt16 = Nn >> 4;
    int jt = rest % nt16;
    int t = rest / nt16;
    int k = t * 32 + fq * 8 + e;
    int n = jt * 16 + fm;
    float w = W[(long long)k * Nn + n];
    unsigned short hb = bf16_bits(w);
    Wh[o] = hb;
    Wl[o] = bf16_bits(w - bf16_f(hb));
    return;
  }
  __shared__ int s_nz;
  __shared__ int cnt[NBMAX];
  __shared__ int scn[NBMAX + 1];
  __shared__ int cur[NBMAX];
  __shared__ int gbase[NBMAX];
  __shared__ unsigned out[CHUNK];
  // inline int64-storage detection (odd 32-bit words of 16 KB sample all zero)
  if (tid == 0) s_nz = 0;
  for (int b = tid; b < NBMAX; b += 256) cnt[b] = 0;
  __syncthreads();
  {
    int nz = 0;
    for (int i = 1 + 2 * tid; i < 4096; i += 512)
      nz |= (((const int*)eidx)[i] != 0);
    if (nz) atomicOr(&s_nz, 1);
  }
  __syncthreads();
  const int is64 = (s_nz == 0) ? 1 : 0;
  const int cs = blockIdx.x * CHUNK;
  const int n = min(CHUNK, E - cs);
  unsigned pk[CHUNK / 256];
#pragma unroll
  for (int it = 0; it < CHUNK / 256; ++it) {
    int i = cs + it * 256 + tid;
    unsigned p = 0xFFFFFFFFu;
    if (i < E) {
      int s = edge_at(eidx, i, is64);
      int d = edge_at(eidx, (long long)E + i, is64);
      p = ((unsigned)d << 16) | (unsigned)s;
      atomicAdd(&cnt[d >> BSHIFT], 1);
    }
    pk[it] = p;
  }
  __syncthreads();
  if (tid < NB) scn[tid + 1] = cnt[tid];
  if (tid == 0) scn[0] = 0;
  __syncthreads();
  for (int off = 1; off < NB; off <<= 1) {
    int t = 0;
    if (tid < NB && tid + 1 > off) t = scn[tid + 1 - off];
    __syncthreads();
    if (tid < NB && tid + 1 > off) scn[tid + 1] += t;
    __syncthreads();
  }
  if (tid < NB) {
    cur[tid] = scn[tid];
    gbase[tid] = (cnt[tid] > 0)
        ? (tid * CAP + atomicAdd(&ccur[tid], cnt[tid])) : 0;
  }
  __syncthreads();
#pragma unroll
  for (int it = 0; it < CHUNK / 256; ++it) {
    unsigned p = pk[it];
    if (p != 0xFFFFFFFFu) {
      int b = (int)(p >> (16 + BSHIFT));
      int pos = atomicAdd(&cur[b], 1);
      out[pos] = p;
    }
  }
  __syncthreads();
  for (int p2 = tid; p2 < n; p2 += 256) {
    unsigned v = out[p2];
    int b = (int)(v >> (16 + BSHIFT));
    pairs[gbase[b] + (p2 - scn[b])] = v;  // contiguous run per bucket
  }
}

// Per-bucket: scan of bucket counts (inlined) + LDS histogram + scan ->
// rowptr/dinv; place src into dense elist window via LDS cursors.
__global__ __launch_bounds__(256) void k_binB(
    const unsigned* __restrict__ pairs, const int* __restrict__ ccur,
    int* __restrict__ rowptr, float* __restrict__ dinv,
    unsigned short* __restrict__ elist, int N, int NB, int E) {
  __shared__ int scn2[NBMAX];
  __shared__ int hist[BSIZE];
  __shared__ int loc[BSIZE];
  const int b = blockIdx.x;
  const int tid = threadIdx.x;
  if (b == 0 && tid == 0) rowptr[N] = E;
  // inclusive scan of ccur over NB buckets (tiny, redone per block)
  if (tid < NBMAX) scn2[tid] = (tid < NB) ? ccur[tid] : 0;
  __syncthreads();
  for (int off = 1; off < NBMAX; off <<= 1) {
    int t = (tid < NBMAX && tid >= off) ? scn2[tid - off] : 0;
    __syncthreads();
    if (tid < NBMAX) scn2[tid] += t;
    __syncthreads();
  }
  const int cntb = ccur[b];
  const int base = scn2[b] - cntb;  // exclusive prefix
  const int nbeg = b * CAP;
  const int j0 = tid, j1 = tid + 256;
  hist[j0] = 0; hist[j1] = 0;
  __syncthreads();
  for (int i = tid; i < cntb; i += 256) {
    unsigned v = pairs[nbeg + i];
    atomicAdd(&hist[(v >> 16) & (BSIZE - 1)], 1);
  }
  __syncthreads();
  loc[j0] = hist[j0]; loc[j1] = hist[j1];
  __syncthreads();
  for (int off = 1; off < BSIZE; off <<= 1) {
    int v0 = (j0 >= off) ? loc[j0 - off] : 0;
    int v1 = (j1 >= off) ? loc[j1 - off] : 0;
    __syncthreads();
    loc[j0] += v0; loc[j1] += v1;
    __syncthreads();
  }
  int c0 = base + loc[j0] - hist[j0];
  int c1 = base + loc[j1] - hist[j1];
  int gd0 = b * BSIZE + j0, gd1 = b * BSIZE + j1;
  if (gd0 < N) { rowptr[gd0] = c0; dinv[gd0] = rsqrtf((float)(hist[j0] + 1)); }
  if (gd1 < N) { rowptr[gd1] = c1; dinv[gd1] = rsqrtf((float)(hist[j1] + 1)); }
  __syncthreads();
  hist[j0] = c0; hist[j1] = c1;  // reuse as cursors
  __syncthreads();
  for (int i = tid; i < cntb; i += 256) {
    unsigned v = pairs[nbeg + i];
    int pos = atomicAdd(&hist[(v >> 16) & (BSIZE - 1)], 1);
    elist[pos] = (unsigned short)(v & 0xFFFFu);
  }
}

// MFMA GEMM (layer 1): Hs(bf16) = (X[M,K] @ W[K,NOUT]) * dinv[row], bf16x3.
// R16 config restored: BM=128, WX=2 (8 waves, TB=512), 391 blocks.
// A: global->reg fp32 dbuf, in-reg bf16 hi/lo split. B: fragment-major prepped
// weights, global_load_lds into dbuf LDS (lane-consecutive 16B reads,
// conflict-free). 1 barrier/K-step.
template <int K, int NOUT, int WM, int WY, int WX, int TB>
__global__ __launch_bounds__(TB) void k_gemm_mfma(
    const float* __restrict__ X, const unsigned short* __restrict__ Whi,
    const unsigned short* __restrict__ Wlo, const float* __restrict__ dinv,
    unsigned short* __restrict__ Hs, int M) {
  constexpr int BM = WM * WY;
  constexpr int BN = NOUT;           // block covers full N
  constexpr int JF = BN / (16 * WX); // j-fragments per wave
  constexpr int KC = 32;
  constexpr int I = WM / 16;
  constexpr int NK = K / KC;
  constexpr int CH = BN * 4;  // 16B chunks per (hi|lo) array per K-step
  static_assert(WY * WX * 64 == TB, "wave grid covers block");
  static_assert(BN % (16 * WX) == 0, "clean j-fragment split");
  // fragment-major B: per buffer, BN/16 col-tiles x 64 lanes x 8 ushorts
  __shared__ unsigned short Bh[2][BN * KC], Bl[2][BN * KC];
  const int tid = threadIdx.x;
  const int lane = tid & 63, wv = tid >> 6;
  const int wy = wv / WX, wx = wv % WX;
  const int fm = lane & 15;
  const int fq = lane >> 4;
  const int base = blockIdx.x * BM;

  f32x4 acc[I][JF];
#pragma unroll
  for (int i = 0; i < I; ++i)
#pragma unroll
    for (int j = 0; j < JF; ++j) acc[i][j] = (f32x4){0.f, 0.f, 0.f, 0.f};

  // A register double-buffer (parity compile-time under unroll 2)
  float4 av[2][I][2];

  auto loadA = [&](int k0, int pb) {
#pragma unroll
    for (int i = 0; i < I; ++i) {
      int row = base + wy * WM + i * 16 + fm;
      av[pb][i][0] = make_float4(0.f, 0.f, 0.f, 0.f);
      av[pb][i][1] = make_float4(0.f, 0.f, 0.f, 0.f);
      if (row < M) {
        const float4* p = (const float4*)&X[(long long)row * K + k0 + fq * 8];
        av[pb][i][0] = p[0];
        av[pb][i][1] = p[1];
      }
    }
  };
  auto issueB = [&](int t, int buf) {
#pragma unroll
    for (int it = 0; it < (CH + TB - 1) / TB; ++it) {
      int cb = it * TB + wv * 64;  // wave-uniform chunk base (16B chunks)
      if (cb < CH) {
        size_t so = (size_t)t * (BN * 32) + (size_t)(cb + lane) * 8;
        gload_lds16(&Whi[so], (unsigned short*)&Bh[buf][0] + (size_t)cb * 8);
        gload_lds16(&Wlo[so], (unsigned short*)&Bl[buf][0] + (size_t)cb * 8);
      }
    }
  };
  auto cvt8 = [&](const float4& a, const float4& b, short8& h, short8& l) {
    float f0 = a.x, f1 = a.y, f2 = a.z, f3 = a.w;
    float f4 = b.x, f5 = b.y, f6 = b.z, f7 = b.w;
    unsigned short hb;
    hb = bf16_bits(f0); h[0] = (short)hb; l[0] = (short)bf16_bits(f0 - bf16_f(hb));
    hb = bf16_bits(f1); h[1] = (short)hb; l[1] = (short)bf16_bits(f1 - bf16_f(hb));
    hb = bf16_bits(f2); h[2] = (short)hb; l[2] = (short)bf16_bits(f2 - bf16_f(hb));
    hb = bf16_bits(f3); h[3] = (short)hb; l[3] = (short)bf16_bits(f3 - bf16_f(hb));
    hb = bf16_bits(f4); h[4] = (short)hb; l[4] = (short)bf16_bits(f4 - bf16_f(hb));
    hb = bf16_bits(f5); h[5] = (short)hb; l[5] = (short)bf16_bits(f5 - bf16_f(hb));
    hb = bf16_bits(f6); h[6] = (short)hb; l[6] = (short)bf16_bits(f6 - bf16_f(hb));
    hb = bf16_bits(f7); h[7] = (short)hb; l[7] = (short)bf16_bits(f7 - bf16_f(hb));
  };

  // prologue: stage tile 0 (B -> LDS buf0 via DMA, A -> registers parity 0)
  issueB(0, 0);
  loadA(0, 0);
  __syncthreads();  // drains vmcnt(0): B(0) in LDS, av(0) in regs

#pragma unroll 2
  for (int t = 0; t < NK; ++t) {
    const int pb = t & 1;
    if (t + 1 < NK) {
      issueB(t + 1, pb ^ 1);        // next B tile: DMA into other buffer
      loadA((t + 1) * KC, pb ^ 1);  // next A tile: global->reg
    }
    // convert current A tile (drained by previous barrier: no stall)
    short8 ah[I], al[I];
#pragma unroll
    for (int i = 0; i < I; ++i) cvt8(av[pb][i][0], av[pb][i][1], ah[i], al[i]);
    // B fragments: lane-consecutive 16B reads (conflict-free)
#pragma unroll
    for (int j = 0; j < JF; ++j) {
      int jt = wx * JF + j;
      short8 bh = *(const short8*)&Bh[pb][jt * 512 + lane * 8];
      short8 bl = *(const short8*)&Bl[pb][jt * 512 + lane * 8];
#pragma unroll
      for (int i = 0; i < I; ++i) {
        acc[i][j] = __builtin_amdgcn_mfma_f32_16x16x32_bf16(ah[i], bh, acc[i][j], 0, 0, 0);
        acc[i][j] = __builtin_amdgcn_mfma_f32_16x16x32_bf16(ah[i], bl, acc[i][j], 0, 0, 0);
        acc[i][j] = __builtin_amdgcn_mfma_f32_16x16x32_bf16(al[i], bh, acc[i][j], 0, 0, 0);
      }
    }
    __syncthreads();  // one barrier per K-step (drains next-tile DMA)
  }

  // epilogue: C/D layout col=lane&15, row=fq*4+reg
#pragma unroll
  for (int i = 0; i < I; ++i) {
#pragma unroll
    for (int reg = 0; reg < 4; ++reg) {
      int row = base + wy * WM + i * 16 + fq * 4 + reg;
      if (row < M) {
        float dv = dinv[row];
#pragma unroll
        for (int j = 0; j < JF; ++j)
          Hs[(long long)row * NOUT + wx * (JF * 16) + j * 16 + fm] =
              bf16_bits(acc[i][j][reg] * dv);
      }
    }
  }
}

// Accumulate 8 bf16 (one uint4) into 8 fp32.
__device__ __forceinline__ void acc8(float* a, uint4 u) {
  const unsigned* p = (const unsigned*)&u;
#pragma unroll
  for (int q = 0; q < 4; ++q) {
    unsigned w = p[q];
    a[2 * q]     += __uint_as_float(w << 16);
    a[2 * q + 1] += __uint_as_float(w & 0xFFFF0000u);
  }
}

// FUSED gather (finish layer 1) + layer-2 transform. Per 64-node block:
// phase 1 (R19): 2-node-per-thread interleaved gather. 16 thread-groups
//   (lane16 = col chunk), 2 passes; each thread walks nodes r and r+16 with
//   dual edge cursors + dual accumulator sets -> 2x outstanding loads/wave.
//   h2row = relu(dinv[n]*(sum Hs[src] + Hs[n]) + b1), split bf16 hi/lo,
//   store as MFMA A-fragments in LDS (XOR-swizzled).
// phase 2: one barrier; Hs2[row] = (h2row @ W2) * dinv[row] via bf16x3 MFMA
//   against fragment-major W2 (L2-hot). 4 waves x 16 rows x 64 cols.
template <int C, int COUT>  // C=128 in, COUT=64 out
__global__ __launch_bounds__(256) void k_gather_gemm(
    const int* __restrict__ rowptr, const unsigned short* __restrict__ elist,
    const float* __restrict__ dinv, const unsigned short* __restrict__ Hs,
    const float* __restrict__ bias,
    const unsigned short* __restrict__ W2h,
    const unsigned short* __restrict__ W2l,
    unsigned short* __restrict__ Hs2, int N) {
  constexpr int NT = C / 32;  // K-steps (4)
  static_assert(C == 128 && COUT == 64, "fused shape");
  __shared__ unsigned short Ah[64 * C], Al[64 * C];  // 16 KB each
  const int tid = threadIdx.x;
  const int lane16 = tid & 15;  // chunk within node row
  const int pgrp = tid >> 4;    // 0..15: thread-group (node pair index)
  const int col = lane16 * 8;
  const int nb = blockIdx.x * 64;

  // ---- phase 1: gather + finish layer-1 rows -> LDS fragments (2 passes,
  //      2 nodes per thread per pass, interleaved)
  for (int q = 0; q < 2; ++q) {
    const int rA = q * 32 + pgrp;
    const int rB = rA + 16;
    const int nodeA = nb + rA, nodeB = nb + rB;
    float aA0[8] = {0, 0, 0, 0, 0, 0, 0, 0};
    float aA1[8] = {0, 0, 0, 0, 0, 0, 0, 0};
    float aB0[8] = {0, 0, 0, 0, 0, 0, 0, 0};
    float aB1[8] = {0, 0, 0, 0, 0, 0, 0, 0};
    int eA = 0, endA = 0, eB = 0, endB = 0;
    if (nodeA < N) {
      eA = rowptr[nodeA]; endA = rowptr[nodeA + 1];
      acc8(aA0, *(const uint4*)&Hs[(long long)nodeA * C + col]);  // self-loop
    }
    if (nodeB < N) {
      eB = rowptr[nodeB]; endB = rowptr[nodeB + 1];
      acc8(aB0, *(const uint4*)&Hs[(long long)nodeB * C + col]);
    }
    // interleaved main loop: 8 loads in flight (4 per node)
    while (eA + 3 < endA && eB + 3 < endB) {
      int sA0 = elist[eA],     sA1 = elist[eA + 1];
      int sA2 = elist[eA + 2], sA3 = elist[eA + 3];
      int sB0 = elist[eB],     sB1 = elist[eB + 1];
      int sB2 = elist[eB + 2], sB3 = elist[eB + 3];
      uint4 vA0 = *(const uint4*)&Hs[(long long)sA0 * C + col];
      uint4 vA1 = *(const uint4*)&Hs[(long long)sA1 * C + col];
      uint4 vA2 = *(const uint4*)&Hs[(long long)sA2 * C + col];
      uint4 vA3 = *(const uint4*)&Hs[(long long)sA3 * C + col];
      uint4 vB0 = *(const uint4*)&Hs[(long long)sB0 * C + col];
      uint4 vB1 = *(const uint4*)&Hs[(long long)sB1 * C + col];
      uint4 vB2 = *(const uint4*)&Hs[(long long)sB2 * C + col];
      uint4 vB3 = *(const uint4*)&Hs[(long long)sB3 * C + col];
      acc8(aA0, vA0); acc8(aA1, vA1); acc8(aA0, vA2); acc8(aA1, vA3);
      acc8(aB0, vB0); acc8(aB1, vB1); acc8(aB0, vB2); acc8(aB1, vB3);
      eA += 4; eB += 4;
    }
    // drain A
    for (; eA + 3 < endA; eA += 4) {
      int s0 = elist[eA],     s1 = elist[eA + 1];
      int s2 = elist[eA + 2], s3 = elist[eA + 3];
      uint4 v0 = *(const uint4*)&Hs[(long long)s0 * C + col];
      uint4 v1 = *(const uint4*)&Hs[(long long)s1 * C + col];
      uint4 v2 = *(const uint4*)&Hs[(long long)s2 * C + col];
      uint4 v3 = *(const uint4*)&Hs[(long long)s3 * C + col];
      acc8(aA0, v0); acc8(aA1, v1); acc8(aA0, v2); acc8(aA1, v3);
    }
    for (; eA < endA; ++eA)
      acc8(aA0, *(const uint4*)&Hs[(long long)elist[eA] * C + col]);
    // drain B
    for (; eB + 3 < endB; eB += 4) {
      int s0 = elist[eB],     s1 = elist[eB + 1];
      int s2 = elist[eB + 2], s3 = elist[eB + 3];
      uint4 v0 = *(const uint4*)&Hs[(long long)s0 * C + col];
      uint4 v1 = *(const uint4*)&Hs[(long long)s1 * C + col];
      uint4 v2 = *(const uint4*)&Hs[(long long)s2 * C + col];
      uint4 v3 = *(const uint4*)&Hs[(long long)s3 * C + col];
      acc8(aB0, v0); acc8(aB1, v1); acc8(aB0, v2); acc8(aB1, v3);
    }
    for (; eB < endB; ++eB)
      acc8(aB0, *(const uint4*)&Hs[(long long)elist[eB] * C + col]);
    // finish + LDS write (both nodes)
    short8 hA = (short8){0,0,0,0,0,0,0,0}, lA = hA;
    short8 hB = hA, lB = hA;
    if (nodeA < N) {
      const float dv = dinv[nodeA];
#pragma unroll
      for (int i = 0; i < 8; ++i) {
        float o = (aA0[i] + aA1[i]) * dv + bias[col + i];
        o = fmaxf(o, 0.f);
        unsigned short hb = bf16_bits(o);
        hA[i] = (short)hb;
        lA[i] = (short)bf16_bits(o - bf16_f(hb));
      }
    }
    if (nodeB < N) {
      const float dv = dinv[nodeB];
#pragma unroll
      for (int i = 0; i < 8; ++i) {
        float o = (aB0[i] + aB1[i]) * dv + bias[col + i];
        o = fmaxf(o, 0.f);
        unsigned short hb = bf16_bits(o);
        hB[i] = (short)hb;
        lB[i] = (short)bf16_bits(o - bf16_f(hb));
      }
    }
    const int wA = rA * C + ((lane16 ^ (rA & 7)) * 8);
    const int wB = rB * C + ((lane16 ^ (rB & 7)) * 8);
    *(short8*)&Ah[wA] = hA;
    *(short8*)&Al[wA] = lA;
    *(short8*)&Ah[wB] = hB;
    *(short8*)&Al[wB] = lB;
  }
  __syncthreads();

  // ---- phase 2: Hs2[row] = (h2row @ W2) * dinv[row]
  const int lane = tid & 63, wv = tid >> 6;  // 4 waves, 16 rows each
  const int fm = lane & 15, fq = lane >> 4;
  f32x4 acc[4];
#pragma unroll
  for (int j = 0; j < 4; ++j) acc[j] = (f32x4){0.f, 0.f, 0.f, 0.f};
#pragma unroll
  for (int t = 0; t < NT; ++t) {
    const int aidx = (wv * 16 + fm) * C + (((t * 4 + fq) ^ (fm & 7)) * 8);
    short8 ah = *(const short8*)&Ah[aidx];
    short8 al = *(const short8*)&Al[aidx];
#pragma unroll
    for (int j = 0; j < 4; ++j) {
      const int so = (t * 4 + j) * 512 + lane * 8;
      short8 bh = *(const short8*)&W2h[so];
      short8 bl = *(const short8*)&W2l[so];
      acc[j] = __builtin_amdgcn_mfma_f32_16x16x32_bf16(ah, bh, acc[j], 0, 0, 0);
      acc[j] = __builtin_amdgcn_mfma_f32_16x16x32_bf16(ah, bl, acc[j], 0, 0, 0);
      acc[j] = __builtin_amdgcn_mfma_f32_16x16x32_bf16(al, bh, acc[j], 0, 0, 0);
    }
  }
#pragma unroll
  for (int reg = 0; reg < 4; ++reg) {
    const int row = nb + wv * 16 + fq * 4 + reg;
    if (row < N) {
      const float dv = dinv[row];
#pragma unroll
      for (int j = 0; j < 4; ++j)
        Hs2[(long long)row * COUT + j * 16 + fm] =
            bf16_bits(acc[j][reg] * dv);
    }
  }
}

// Gather-aggregate from bf16 Hs (final layer, fp32 out):
// OUT[d] = dinv[d] * (sum_{s in in(d)} Hs[s] + Hs[d]) + bias.
template <int C, bool RELU>
__global__ __launch_bounds__(256) void k_gather(
    const int* __restrict__ rowptr, const unsigned short* __restrict__ elist,
    const float* __restrict__ dinv, const unsigned short* __restrict__ Hs,
    const float* __restrict__ bias, float* __restrict__ OUT, int N) {
  constexpr int TPN = C / 8;      // threads per node (8 bf16 = 16 B each)
  constexpr int NPB = 256 / TPN;  // nodes per block
  const int node = blockIdx.x * NPB + (int)threadIdx.x / TPN;
  const int lane = (int)threadIdx.x % TPN;
  if (node >= N) return;
  const int col = lane * 8;
  const int beg = rowptr[node];
  const int end = rowptr[node + 1];
  float a0[8] = {0, 0, 0, 0, 0, 0, 0, 0};
  float a1[8] = {0, 0, 0, 0, 0, 0, 0, 0};
  acc8(a0, *(const uint4*)&Hs[(long long)node * C + col]);  // self-loop
  int e = beg;
  for (; e + 7 < end; e += 8) {  // unroll 8: deeper MLP
    int s0 = elist[e],     s1 = elist[e + 1];
    int s2 = elist[e + 2], s3 = elist[e + 3];
    int s4 = elist[e + 4], s5 = elist[e + 5];
    int s6 = elist[e + 6], s7 = elist[e + 7];
    uint4 v0 = *(const uint4*)&Hs[(long long)s0 * C + col];
    uint4 v1 = *(const uint4*)&Hs[(long long)s1 * C + col];
    uint4 v2 = *(const uint4*)&Hs[(long long)s2 * C + col];
    uint4 v3 = *(const uint4*)&Hs[(long long)s3 * C + col];
    uint4 v4 = *(const uint4*)&Hs[(long long)s4 * C + col];
    uint4 v5 = *(const uint4*)&Hs[(long long)s5 * C + col];
    uint4 v6 = *(const uint4*)&Hs[(long long)s6 * C + col];
    uint4 v7 = *(const uint4*)&Hs[(long long)s7 * C + col];
    acc8(a0, v0); acc8(a1, v1); acc8(a0, v2); acc8(a1, v3);
    acc8(a0, v4); acc8(a1, v5); acc8(a0, v6); acc8(a1, v7);
  }
  for (; e < end; ++e) {
    uint4 v0 = *(const uint4*)&Hs[(long long)elist[e] * C + col];
    acc8(a0, v0);
  }
  const float dv = dinv[node];
  float o[8];
#pragma unroll
  for (int i = 0; i < 8; ++i) {
    o[i] = (a0[i] + a1[i]) * dv + bias[col + i];
    if (RELU) o[i] = fmaxf(o[i], 0.f);
  }
  *(float4*)&OUT[(long long)node * C + col] = make_float4(o[0], o[1], o[2], o[3]);
  *(float4*)&OUT[(long long)node * C + col + 4] = make_float4(o[4], o[5], o[6], o[7]);
}

extern "C" void kernel_launch(void* const* d_in, const int* in_sizes, int n_in,
                              void* d_out, int out_size, void* d_ws, size_t ws_size,
                              hipStream_t stream) {
  const float* x  = (const float*)d_in[0];
  const void*  ei = d_in[1];
  const float* W1 = (const float*)d_in[2];
  const float* b1 = (const float*)d_in[3];
  const float* W2 = (const float*)d_in[4];
  const float* b2 = (const float*)d_in[5];
  float* out = (float*)d_out;
  const int N = in_sizes[0] / 512;  // 50000
  const int E = in_sizes[1] / 2;    // 1600000
  const int NB = (N + BSIZE - 1) >> BSHIFT;       // 98
  const int nchunks = (E + CHUNK - 1) / CHUNK;    // 391

  char* ws = (char*)d_ws;
  size_t off = 0;
  auto take = [&](size_t bytes) {
    void* p = ws + off;
    off = (off + bytes + 255) & ~(size_t)255;
    return p;
  };
  float* dinv   = (float*)take((size_t)N * 4);
  int*   rowptr = (int*)take((size_t)(N + 1) * 4);
  int*   ccur   = (int*)take((size_t)NBMAX * 4);
  unsigned short* elist = (unsigned short*)take((size_t)E * 2);
  unsigned short* Wt1h = (unsigned short*)take((size_t)512 * 128 * 2);
  unsigned short* Wt1l = (unsigned short*)take((size_t)512 * 128 * 2);
  unsigned short* Wt2h = (unsigned short*)take((size_t)128 * 64 * 2);
  unsigned short* Wt2l = (unsigned short*)take((size_t)128 * 64 * 2);
  unsigned short* Hs  = (unsigned short*)take((size_t)N * 128 * 2);  // bf16
  unsigned short* Hs2 = (unsigned short*)take((size_t)N * 64 * 2);   // bf16
  unsigned* pairs = (unsigned*)take((size_t)NBMAX * CAP * 4);  // 16.8 MB

  const int B = 256;
  constexpr int WJOBS = (512 * 128 + 128 * 64) / 256;  // 288
  // CSR build + weight prep (2 kernels + 1 memset)
  hipMemsetAsync(ccur, 0, (size_t)NBMAX * 4, stream);
  k_binA<<<nchunks + WJOBS, B, 0, stream>>>(ei, ccur, pairs,
                                            W1, Wt1h, Wt1l, W2, Wt2h, Wt2l,
                                            E, NB, nchunks);
  k_binB<<<NB, B, 0, stream>>>(pairs, ccur, rowptr, dinv, elist, N, NB, E);
  // layer 1 GEMM: BM=128 (WM=32, WY=4, WX=2), 8 waves, 391 blocks (R16 cfg)
  k_gemm_mfma<512, 128, 32, 4, 2, 512><<<(N + 127) / 128, 512, 0, stream>>>(
      x, Wt1h, Wt1l, dinv, Hs, N);
  // FUSED gather1 + layer-2 transform: 782 blocks x 64 nodes, 2-node ILP
  k_gather_gemm<128, 64><<<(N + 63) / 64, B, 0, stream>>>(
      rowptr, elist, dinv, Hs, b1, Wt2h, Wt2l, Hs2, N);
  // final gather (bias b2, no relu, fp32 out)
  k_gather<64, false><<<(N + 31) / 32, B, 0, stream>>>(rowptr, elist, dinv, Hs2, b2, out, N);
}

// Round 11
// 309.001 us; speedup vs baseline: 1.0657x; 1.0657x over previous
//
#include <hip/hip_runtime.h>
#include <hip/hip_bf16.h>

// GCN 2-layer: out = A' relu(A' (xW1) + b1) W2 + b2, A' = D^-1/2 (A+I) D^-1/2
// R20: post-mortem R19: 2-node ILP regressed (gather at random-access service
// wall; latency theory falsified twice) -> gather_gemm reverted to R17 form.
// New lever: CSR build granularity. binB had 98 blocks (38% machine coverage)
// with 2x512-wide scans + 33K LDS atomics per block. BSHIFT 9->8:
//  - 196 buckets of 256 nodes: binB = 196 blocks (77% coverage), half the
//    per-block work, 1-elem-per-thread scans (fewer barriers).
//  - binA: 196-way LDS counting sort (less atomic contention), CAP=16384.
// R16 base otherwise: gemm1 BM=128/WX=2; fused gather1+layer2-GEMM;
// fragment-major prepped weights; ushort elist; bf16 Hs/Hs2; 5 kernels+memset.

typedef __attribute__((ext_vector_type(8))) short short8;
typedef __attribute__((ext_vector_type(4))) float f32x4;

#define BSHIFT 8
#define BSIZE 256
constexpr int NBMAX = 256;
constexpr int CAP = 16384;   // pair slots per coarse bucket (mean ~8.2K)
constexpr int CHUNK = 4096;  // edges per binA block

__device__ __forceinline__ unsigned short bf16_bits(float f) {
  __hip_bfloat16 h = __float2bfloat16(f);
  return *(unsigned short*)&h;
}
__device__ __forceinline__ float bf16_f(unsigned short u) {
  __hip_bfloat16 h = *(__hip_bfloat16*)&u;
  return __bfloat162float(h);
}
__device__ __forceinline__ void gload_lds16(const void* g, void* l) {
  __builtin_amdgcn_global_load_lds(
      (const __attribute__((address_space(1))) unsigned*)g,
      (__attribute__((address_space(3))) unsigned*)l, 16, 0, 0);
}
__device__ __forceinline__ int edge_at(const void* p, long long i, int is64) {
  return is64 ? (int)((const long long*)p)[i] : ((const int*)p)[i];
}

// Coarse binning (blocks < nchunks): LDS counting-sort of a 4096-edge chunk by
// bucket = d>>8, flush contiguous runs into per-bucket pair regions.
// Blocks >= nchunks: weight prep, fp32 W[K,N] -> FRAGMENT-MAJOR bf16 hi/lo:
//   out[o], o = ((t*(N/16) + jt)*4 + fq)*128 + fm*8 + e
//   holds W[k = t*32 + fq*8 + e][n = jt*16 + fm]
// so each K-step's B image is a contiguous N*32-ushort slice in MFMA fragment
// order (lane = fq*16+fm reads its own 16B at lane*16).
__global__ __launch_bounds__(256) void k_binA(
    const void* __restrict__ eidx, int* __restrict__ ccur,
    unsigned* __restrict__ pairs,
    const float* __restrict__ W1, unsigned short* __restrict__ W1h,
    unsigned short* __restrict__ W1l,
    const float* __restrict__ W2, unsigned short* __restrict__ W2h,
    unsigned short* __restrict__ W2l, int E, int NB, int nchunks) {
  const int tid = threadIdx.x;
  if ((int)blockIdx.x >= nchunks) {  // ---- weight prep ----
    int o = ((int)blockIdx.x - nchunks) * 256 + tid;
    const float* W; unsigned short *Wh, *Wl; int Nn;
    if (o < 512 * 128) { W = W1; Wh = W1h; Wl = W1l; Nn = 128; }
    else { o -= 512 * 128; if (o >= 128 * 64) return;
           W = W2; Wh = W2h; Wl = W2l; Nn = 64; }
    int e = o & 7;
    int fm = (o >> 3) & 15;
    int fq = (o >> 7) & 3;
    int rest = o >> 9;            // t*(Nn/16) + jt
    int nt16 = Nn >> 4;
    int jt = rest % nt16;
    int t = rest / nt16;
    int k = t * 32 + fq * 8 + e;
    int n = jt * 16 + fm;
    float w = W[(long long)k * Nn + n];
    unsigned short hb = bf16_bits(w);
    Wh[o] = hb;
    Wl[o] = bf16_bits(w - bf16_f(hb));
    return;
  }
  __shared__ int s_nz;
  __shared__ int cnt[NBMAX];
  __shared__ int scn[NBMAX + 1];
  __shared__ int cur[NBMAX];
  __shared__ int gbase[NBMAX];
  __shared__ unsigned out[CHUNK];
  // inline int64-storage detection (odd 32-bit words of 16 KB sample all zero)
  if (tid == 0) s_nz = 0;
  for (int b = tid; b < NBMAX; b += 256) cnt[b] = 0;
  __syncthreads();
  {
    int nz = 0;
    for (int i = 1 + 2 * tid; i < 4096; i += 512)
      nz |= (((const int*)eidx)[i] != 0);
    if (nz) atomicOr(&s_nz, 1);
  }
  __syncthreads();
  const int is64 = (s_nz == 0) ? 1 : 0;
  const int cs = blockIdx.x * CHUNK;
  const int n = min(CHUNK, E - cs);
  unsigned pk[CHUNK / 256];
#pragma unroll
  for (int it = 0; it < CHUNK / 256; ++it) {
    int i = cs + it * 256 + tid;
    unsigned p = 0xFFFFFFFFu;
    if (i < E) {
      int s = edge_at(eidx, i, is64);
      int d = edge_at(eidx, (long long)E + i, is64);
      p = ((unsigned)d << 16) | (unsigned)s;
      atomicAdd(&cnt[d >> BSHIFT], 1);
    }
    pk[it] = p;
  }
  __syncthreads();
  if (tid < NB) scn[tid + 1] = cnt[tid];
  if (tid == 0) scn[0] = 0;
  __syncthreads();
  for (int off = 1; off < NB; off <<= 1) {
    int t = 0;
    if (tid < NB && tid + 1 > off) t = scn[tid + 1 - off];
    __syncthreads();
    if (tid < NB && tid + 1 > off) scn[tid + 1] += t;
    __syncthreads();
  }
  if (tid < NB) {
    cur[tid] = scn[tid];
    gbase[tid] = (cnt[tid] > 0)
        ? (tid * CAP + atomicAdd(&ccur[tid], cnt[tid])) : 0;
  }
  __syncthreads();
#pragma unroll
  for (int it = 0; it < CHUNK / 256; ++it) {
    unsigned p = pk[it];
    if (p != 0xFFFFFFFFu) {
      int b = (int)(p >> (16 + BSHIFT));
      int pos = atomicAdd(&cur[b], 1);
      out[pos] = p;
    }
  }
  __syncthreads();
  for (int p2 = tid; p2 < n; p2 += 256) {
    unsigned v = out[p2];
    int b = (int)(v >> (16 + BSHIFT));
    pairs[gbase[b] + (p2 - scn[b])] = v;  // contiguous run per bucket
  }
}

// Per-bucket (256 nodes): scan of bucket counts (inlined) + LDS histogram +
// scan -> rowptr/dinv; place src into dense elist window via LDS cursors.
// 1 element per thread throughout (BSIZE == blockDim).
__global__ __launch_bounds__(256) void k_binB(
    const unsigned* __restrict__ pairs, const int* __restrict__ ccur,
    int* __restrict__ rowptr, float* __restrict__ dinv,
    unsigned short* __restrict__ elist, int N, int NB, int E) {
  __shared__ int scn2[NBMAX];
  __shared__ int hist[BSIZE];
  __shared__ int loc[BSIZE];
  const int b = blockIdx.x;
  const int tid = threadIdx.x;
  if (b == 0 && tid == 0) rowptr[N] = E;
  // inclusive scan of ccur over NB buckets (tiny, redone per block)
  scn2[tid] = (tid < NB) ? ccur[tid] : 0;
  __syncthreads();
  for (int off = 1; off < NBMAX; off <<= 1) {
    int t = (tid >= off) ? scn2[tid - off] : 0;
    __syncthreads();
    scn2[tid] += t;
    __syncthreads();
  }
  const int cntb = ccur[b];
  const int base = scn2[b] - cntb;  // exclusive prefix
  const int nbeg = b * CAP;
  hist[tid] = 0;
  __syncthreads();
  for (int i = tid; i < cntb; i += 256) {
    unsigned v = pairs[nbeg + i];
    atomicAdd(&hist[(v >> 16) & (BSIZE - 1)], 1);
  }
  __syncthreads();
  loc[tid] = hist[tid];
  __syncthreads();
  for (int off = 1; off < BSIZE; off <<= 1) {
    int v0 = (tid >= off) ? loc[tid - off] : 0;
    __syncthreads();
    loc[tid] += v0;
    __syncthreads();
  }
  const int c0 = base + loc[tid] - hist[tid];
  const int gd0 = b * BSIZE + tid;
  if (gd0 < N) { rowptr[gd0] = c0; dinv[gd0] = rsqrtf((float)(hist[tid] + 1)); }
  __syncthreads();
  hist[tid] = c0;  // reuse as cursor
  __syncthreads();
  for (int i = tid; i < cntb; i += 256) {
    unsigned v = pairs[nbeg + i];
    int pos = atomicAdd(&hist[(v >> 16) & (BSIZE - 1)], 1);
    elist[pos] = (unsigned short)(v & 0xFFFFu);
  }
}

// MFMA GEMM (layer 1): Hs(bf16) = (X[M,K] @ W[K,NOUT]) * dinv[row], bf16x3.
// R16 config: BM=128, WX=2 (8 waves, TB=512), 391 blocks.
// A: global->reg fp32 dbuf, in-reg bf16 hi/lo split. B: fragment-major prepped
// weights, global_load_lds into dbuf LDS (lane-consecutive 16B reads,
// conflict-free). 1 barrier/K-step.
template <int K, int NOUT, int WM, int WY, int WX, int TB>
__global__ __launch_bounds__(TB) void k_gemm_mfma(
    const float* __restrict__ X, const unsigned short* __restrict__ Whi,
    const unsigned short* __restrict__ Wlo, const float* __restrict__ dinv,
    unsigned short* __restrict__ Hs, int M) {
  constexpr int BM = WM * WY;
  constexpr int BN = NOUT;           // block covers full N
  constexpr int JF = BN / (16 * WX); // j-fragments per wave
  constexpr int KC = 32;
  constexpr int I = WM / 16;
  constexpr int NK = K / KC;
  constexpr int CH = BN * 4;  // 16B chunks per (hi|lo) array per K-step
  static_assert(WY * WX * 64 == TB, "wave grid covers block");
  static_assert(BN % (16 * WX) == 0, "clean j-fragment split");
  // fragment-major B: per buffer, BN/16 col-tiles x 64 lanes x 8 ushorts
  __shared__ unsigned short Bh[2][BN * KC], Bl[2][BN * KC];
  const int tid = threadIdx.x;
  const int lane = tid & 63, wv = tid >> 6;
  const int wy = wv / WX, wx = wv % WX;
  const int fm = lane & 15;
  const int fq = lane >> 4;
  const int base = blockIdx.x * BM;

  f32x4 acc[I][JF];
#pragma unroll
  for (int i = 0; i < I; ++i)
#pragma unroll
    for (int j = 0; j < JF; ++j) acc[i][j] = (f32x4){0.f, 0.f, 0.f, 0.f};

  // A register double-buffer (parity compile-time under unroll 2)
  float4 av[2][I][2];

  auto loadA = [&](int k0, int pb) {
#pragma unroll
    for (int i = 0; i < I; ++i) {
      int row = base + wy * WM + i * 16 + fm;
      av[pb][i][0] = make_float4(0.f, 0.f, 0.f, 0.f);
      av[pb][i][1] = make_float4(0.f, 0.f, 0.f, 0.f);
      if (row < M) {
        const float4* p = (const float4*)&X[(long long)row * K + k0 + fq * 8];
        av[pb][i][0] = p[0];
        av[pb][i][1] = p[1];
      }
    }
  };
  auto issueB = [&](int t, int buf) {
#pragma unroll
    for (int it = 0; it < (CH + TB - 1) / TB; ++it) {
      int cb = it * TB + wv * 64;  // wave-uniform chunk base (16B chunks)
      if (cb < CH) {
        size_t so = (size_t)t * (BN * 32) + (size_t)(cb + lane) * 8;
        gload_lds16(&Whi[so], (unsigned short*)&Bh[buf][0] + (size_t)cb * 8);
        gload_lds16(&Wlo[so], (unsigned short*)&Bl[buf][0] + (size_t)cb * 8);
      }
    }
  };
  auto cvt8 = [&](const float4& a, const float4& b, short8& h, short8& l) {
    float f0 = a.x, f1 = a.y, f2 = a.z, f3 = a.w;
    float f4 = b.x, f5 = b.y, f6 = b.z, f7 = b.w;
    unsigned short hb;
    hb = bf16_bits(f0); h[0] = (short)hb; l[0] = (short)bf16_bits(f0 - bf16_f(hb));
    hb = bf16_bits(f1); h[1] = (short)hb; l[1] = (short)bf16_bits(f1 - bf16_f(hb));
    hb = bf16_bits(f2); h[2] = (short)hb; l[2] = (short)bf16_bits(f2 - bf16_f(hb));
    hb = bf16_bits(f3); h[3] = (short)hb; l[3] = (short)bf16_bits(f3 - bf16_f(hb));
    hb = bf16_bits(f4); h[4] = (short)hb; l[4] = (short)bf16_bits(f4 - bf16_f(hb));
    hb = bf16_bits(f5); h[5] = (short)hb; l[5] = (short)bf16_bits(f5 - bf16_f(hb));
    hb = bf16_bits(f6); h[6] = (short)hb; l[6] = (short)bf16_bits(f6 - bf16_f(hb));
    hb = bf16_bits(f7); h[7] = (short)hb; l[7] = (short)bf16_bits(f7 - bf16_f(hb));
  };

  // prologue: stage tile 0 (B -> LDS buf0 via DMA, A -> registers parity 0)
  issueB(0, 0);
  loadA(0, 0);
  __syncthreads();  // drains vmcnt(0): B(0) in LDS, av(0) in regs

#pragma unroll 2
  for (int t = 0; t < NK; ++t) {
    const int pb = t & 1;
    if (t + 1 < NK) {
      issueB(t + 1, pb ^ 1);        // next B tile: DMA into other buffer
      loadA((t + 1) * KC, pb ^ 1);  // next A tile: global->reg
    }
    // convert current A tile (drained by previous barrier: no stall)
    short8 ah[I], al[I];
#pragma unroll
    for (int i = 0; i < I; ++i) cvt8(av[pb][i][0], av[pb][i][1], ah[i], al[i]);
    // B fragments: lane-consecutive 16B reads (conflict-free)
#pragma unroll
    for (int j = 0; j < JF; ++j) {
      int jt = wx * JF + j;
      short8 bh = *(const short8*)&Bh[pb][jt * 512 + lane * 8];
      short8 bl = *(const short8*)&Bl[pb][jt * 512 + lane * 8];
#pragma unroll
      for (int i = 0; i < I; ++i) {
        acc[i][j] = __builtin_amdgcn_mfma_f32_16x16x32_bf16(ah[i], bh, acc[i][j], 0, 0, 0);
        acc[i][j] = __builtin_amdgcn_mfma_f32_16x16x32_bf16(ah[i], bl, acc[i][j], 0, 0, 0);
        acc[i][j] = __builtin_amdgcn_mfma_f32_16x16x32_bf16(al[i], bh, acc[i][j], 0, 0, 0);
      }
    }
    __syncthreads();  // one barrier per K-step (drains next-tile DMA)
  }

  // epilogue: C/D layout col=lane&15, row=fq*4+reg
#pragma unroll
  for (int i = 0; i < I; ++i) {
#pragma unroll
    for (int reg = 0; reg < 4; ++reg) {
      int row = base + wy * WM + i * 16 + fq * 4 + reg;
      if (row < M) {
        float dv = dinv[row];
#pragma unroll
        for (int j = 0; j < JF; ++j)
          Hs[(long long)row * NOUT + wx * (JF * 16) + j * 16 + fm] =
              bf16_bits(acc[i][j][reg] * dv);
      }
    }
  }
}

// Accumulate 8 bf16 (one uint4) into 8 fp32.
__device__ __forceinline__ void acc8(float* a, uint4 u) {
  const unsigned* p = (const unsigned*)&u;
#pragma unroll
  for (int q = 0; q < 4; ++q) {
    unsigned w = p[q];
    a[2 * q]     += __uint_as_float(w << 16);
    a[2 * q + 1] += __uint_as_float(w & 0xFFFF0000u);
  }
}

// FUSED gather (finish layer 1) + layer-2 transform. Per 64-node block:
// phase 1: h2row = relu(dinv[n]*(sum_{s in in(n)} Hs[s] + Hs[n]) + b1),
//   split to bf16 hi/lo, store as MFMA A-fragments in LDS (XOR-swizzled).
// phase 2: one barrier; Hs2[row] = (h2row @ W2) * dinv[row] via bf16x3 MFMA
//   against fragment-major W2 (L2-hot). 4 waves x 16 rows x 64 cols.
template <int C, int COUT>  // C=128 in, COUT=64 out
__global__ __launch_bounds__(256) void k_gather_gemm(
    const int* __restrict__ rowptr, const unsigned short* __restrict__ elist,
    const float* __restrict__ dinv, const unsigned short* __restrict__ Hs,
    const float* __restrict__ bias,
    const unsigned short* __restrict__ W2h,
    const unsigned short* __restrict__ W2l,
    unsigned short* __restrict__ Hs2, int N) {
  constexpr int NT = C / 32;  // K-steps (4)
  static_assert(C == 128 && COUT == 64, "fused shape");
  __shared__ unsigned short Ah[64 * C], Al[64 * C];  // 16 KB each
  const int tid = threadIdx.x;
  const int lane16 = tid & 15;  // chunk within node row
  const int rl0 = tid >> 4;     // 0..15: node within round

  const int nb = blockIdx.x * 64;

  // ---- phase 1: gather + finish layer-1 rows -> LDS fragments
  for (int rnd = 0; rnd < 4; ++rnd) {
    const int r = rnd * 16 + rl0;
    const int node = nb + r;
    short8 h = (short8){0, 0, 0, 0, 0, 0, 0, 0};
    short8 l = h;
    if (node < N) {
      const int col = lane16 * 8;
      const int beg = rowptr[node];
      const int end = rowptr[node + 1];
      float a0[8] = {0, 0, 0, 0, 0, 0, 0, 0};
      float a1[8] = {0, 0, 0, 0, 0, 0, 0, 0};
      acc8(a0, *(const uint4*)&Hs[(long long)node * C + col]);  // self-loop
      int e = beg;
      for (; e + 7 < end; e += 8) {  // unroll 8
        int s0 = elist[e],     s1 = elist[e + 1];
        int s2 = elist[e + 2], s3 = elist[e + 3];
        int s4 = elist[e + 4], s5 = elist[e + 5];
        int s6 = elist[e + 6], s7 = elist[e + 7];
        uint4 v0 = *(const uint4*)&Hs[(long long)s0 * C + col];
        uint4 v1 = *(const uint4*)&Hs[(long long)s1 * C + col];
        uint4 v2 = *(const uint4*)&Hs[(long long)s2 * C + col];
        uint4 v3 = *(const uint4*)&Hs[(long long)s3 * C + col];
        uint4 v4 = *(const uint4*)&Hs[(long long)s4 * C + col];
        uint4 v5 = *(const uint4*)&Hs[(long long)s5 * C + col];
        uint4 v6 = *(const uint4*)&Hs[(long long)s6 * C + col];
        uint4 v7 = *(const uint4*)&Hs[(long long)s7 * C + col];
        acc8(a0, v0); acc8(a1, v1); acc8(a0, v2); acc8(a1, v3);
        acc8(a0, v4); acc8(a1, v5); acc8(a0, v6); acc8(a1, v7);
      }
      for (; e < end; ++e) {
        uint4 v0 = *(const uint4*)&Hs[(long long)elist[e] * C + col];
        acc8(a0, v0);
      }
      const float dv = dinv[node];
#pragma unroll
      for (int i = 0; i < 8; ++i) {
        float o = (a0[i] + a1[i]) * dv + bias[col + i];
        o = fmaxf(o, 0.f);
        unsigned short hb = bf16_bits(o);
        h[i] = (short)hb;
        l[i] = (short)bf16_bits(o - bf16_f(hb));
      }
    }
    const int widx = r * C + ((lane16 ^ (r & 7)) * 8);
    *(short8*)&Ah[widx] = h;
    *(short8*)&Al[widx] = l;
  }
  __syncthreads();

  // ---- phase 2: Hs2[row] = (h2row @ W2) * dinv[row]
  const int lane = tid & 63, wv = tid >> 6;  // 4 waves, 16 rows each
  const int fm = lane & 15, fq = lane >> 4;
  f32x4 acc[4];
#pragma unroll
  for (int j = 0; j < 4; ++j) acc[j] = (f32x4){0.f, 0.f, 0.f, 0.f};
#pragma unroll
  for (int t = 0; t < NT; ++t) {
    const int aidx = (wv * 16 + fm) * C + (((t * 4 + fq) ^ (fm & 7)) * 8);
    short8 ah = *(const short8*)&Ah[aidx];
    short8 al = *(const short8*)&Al[aidx];
#pragma unroll
    for (int j = 0; j < 4; ++j) {
      const int so = (t * 4 + j) * 512 + lane * 8;
      short8 bh = *(const short8*)&W2h[so];
      short8 bl = *(const short8*)&W2l[so];
      acc[j] = __builtin_amdgcn_mfma_f32_16x16x32_bf16(ah, bh, acc[j], 0, 0, 0);
      acc[j] = __builtin_amdgcn_mfma_f32_16x16x32_bf16(ah, bl, acc[j], 0, 0, 0);
      acc[j] = __builtin_amdgcn_mfma_f32_16x16x32_bf16(al, bh, acc[j], 0, 0, 0);
    }
  }
#pragma unroll
  for (int reg = 0; reg < 4; ++reg) {
    const int row = nb + wv * 16 + fq * 4 + reg;
    if (row < N) {
      const float dv = dinv[row];
#pragma unroll
      for (int j = 0; j < 4; ++j)
        Hs2[(long long)row * COUT + j * 16 + fm] =
            bf16_bits(acc[j][reg] * dv);
    }
  }
}

// Gather-aggregate from bf16 Hs (final layer, fp32 out):
// OUT[d] = dinv[d] * (sum_{s in in(d)} Hs[s] + Hs[d]) + bias.
template <int C, bool RELU>
__global__ __launch_bounds__(256) void k_gather(
    const int* __restrict__ rowptr, const unsigned short* __restrict__ elist,
    const float* __restrict__ dinv, const unsigned short* __restrict__ Hs,
    const float* __restrict__ bias, float* __restrict__ OUT, int N) {
  constexpr int TPN = C / 8;      // threads per node (8 bf16 = 16 B each)
  constexpr int NPB = 256 / TPN;  // nodes per block
  const int node = blockIdx.x * NPB + (int)threadIdx.x / TPN;
  const int lane = (int)threadIdx.x % TPN;
  if (node >= N) return;
  const int col = lane * 8;
  const int beg = rowptr[node];
  const int end = rowptr[node + 1];
  float a0[8] = {0, 0, 0, 0, 0, 0, 0, 0};
  float a1[8] = {0, 0, 0, 0, 0, 0, 0, 0};
  acc8(a0, *(const uint4*)&Hs[(long long)node * C + col]);  // self-loop
  int e = beg;
  for (; e + 7 < end; e += 8) {  // unroll 8
    int s0 = elist[e],     s1 = elist[e + 1];
    int s2 = elist[e + 2], s3 = elist[e + 3];
    int s4 = elist[e + 4], s5 = elist[e + 5];
    int s6 = elist[e + 6], s7 = elist[e + 7];
    uint4 v0 = *(const uint4*)&Hs[(long long)s0 * C + col];
    uint4 v1 = *(const uint4*)&Hs[(long long)s1 * C + col];
    uint4 v2 = *(const uint4*)&Hs[(long long)s2 * C + col];
    uint4 v3 = *(const uint4*)&Hs[(long long)s3 * C + col];
    uint4 v4 = *(const uint4*)&Hs[(long long)s4 * C + col];
    uint4 v5 = *(const uint4*)&Hs[(long long)s5 * C + col];
    uint4 v6 = *(const uint4*)&Hs[(long long)s6 * C + col];
    uint4 v7 = *(const uint4*)&Hs[(long long)s7 * C + col];
    acc8(a0, v0); acc8(a1, v1); acc8(a0, v2); acc8(a1, v3);
    acc8(a0, v4); acc8(a1, v5); acc8(a0, v6); acc8(a1, v7);
  }
  for (; e < end; ++e) {
    uint4 v0 = *(const uint4*)&Hs[(long long)elist[e] * C + col];
    acc8(a0, v0);
  }
  const float dv = dinv[node];
  float o[8];
#pragma unroll
  for (int i = 0; i < 8; ++i) {
    o[i] = (a0[i] + a1[i]) * dv + bias[col + i];
    if (RELU) o[i] = fmaxf(o[i], 0.f);
  }
  *(float4*)&OUT[(long long)node * C + col] = make_float4(o[0], o[1], o[2], o[3]);
  *(float4*)&OUT[(long long)node * C + col + 4] = make_float4(o[4], o[5], o[6], o[7]);
}

extern "C" void kernel_launch(void* const* d_in, const int* in_sizes, int n_in,
                              void* d_out, int out_size, void* d_ws, size_t ws_size,
                              hipStream_t stream) {
  const float* x  = (const float*)d_in[0];
  const void*  ei = d_in[1];
  const float* W1 = (const float*)d_in[2];
  const float* b1 = (const float*)d_in[3];
  const float* W2 = (const float*)d_in[4];
  const float* b2 = (const float*)d_in[5];
  float* out = (float*)d_out;
  const int N = in_sizes[0] / 512;  // 50000
  const int E = in_sizes[1] / 2;    // 1600000
  const int NB = (N + BSIZE - 1) >> BSHIFT;       // 196
  const int nchunks = (E + CHUNK - 1) / CHUNK;    // 391

  char* ws = (char*)d_ws;
  size_t off = 0;
  auto take = [&](size_t bytes) {
    void* p = ws + off;
    off = (off + bytes + 255) & ~(size_t)255;
    return p;
  };
  float* dinv   = (float*)take((size_t)N * 4);
  int*   rowptr = (int*)take((size_t)(N + 1) * 4);
  int*   ccur   = (int*)take((size_t)NBMAX * 4);
  unsigned short* elist = (unsigned short*)take((size_t)E * 2);
  unsigned short* Wt1h = (unsigned short*)take((size_t)512 * 128 * 2);
  unsigned short* Wt1l = (unsigned short*)take((size_t)512 * 128 * 2);
  unsigned short* Wt2h = (unsigned short*)take((size_t)128 * 64 * 2);
  unsigned short* Wt2l = (unsigned short*)take((size_t)128 * 64 * 2);
  unsigned short* Hs  = (unsigned short*)take((size_t)N * 128 * 2);  // bf16
  unsigned short* Hs2 = (unsigned short*)take((size_t)N * 64 * 2);   // bf16
  unsigned* pairs = (unsigned*)take((size_t)NBMAX * CAP * 4);  // 16.8 MB

  const int B = 256;
  constexpr int WJOBS = (512 * 128 + 128 * 64) / 256;  // 288
  // CSR build + weight prep (2 kernels + 1 memset)
  hipMemsetAsync(ccur, 0, (size_t)NBMAX * 4, stream);
  k_binA<<<nchunks + WJOBS, B, 0, stream>>>(ei, ccur, pairs,
                                            W1, Wt1h, Wt1l, W2, Wt2h, Wt2l,
                                            E, NB, nchunks);
  k_binB<<<NB, B, 0, stream>>>(pairs, ccur, rowptr, dinv, elist, N, NB, E);
  // layer 1 GEMM: BM=128 (WM=32, WY=4, WX=2), 8 waves, 391 blocks (R16 cfg)
  k_gemm_mfma<512, 128, 32, 4, 2, 512><<<(N + 127) / 128, 512, 0, stream>>>(
      x, Wt1h, Wt1l, dinv, Hs, N);
  // FUSED gather1 + layer-2 transform: 782 blocks x 64 nodes
  k_gather_gemm<128, 64><<<(N + 63) / 64, B, 0, stream>>>(
      rowptr, elist, dinv, Hs, b1, Wt2h, Wt2l, Hs2, N);
  // final gather (bias b2, no relu, fp32 out)
  k_gather<64, false><<<(N + 31) / 32, B, 0, stream>>>(rowptr, elist, dinv, Hs2, b2, out, N);
}